// Round 8
// baseline (17623.483 us; speedup 1.0000x reference)
//
#include <hip/hip_runtime.h>
#include <hip/hip_bf16.h>

// alphaLSTMNetwork: B=2048 sequential steps, E=16 elevators.
// R8: producer-consumer mega-kernel. Blocks 0-15 = k2 (proven R4 code) producing
// x per 128-step chunk; blocks 16-31 = fused comm+out-LSTM consumer:
//   phase A: 1 wave per timestep computes gih inline (LDS-staged Wih0^T fp32 +
//            fp16-dot2 recurrent parts) + 48-step comm chain -> grp
//   phase B: cross-block flag, stage grp chunk to LDS (packed fp16)
//   phase C: R3-style out-LSTM recurrence, gg computed in-flight (32 fdot2)
// Sync: __syncthreads (drains vmcnt) + __threadfence + device atomicAdd;
// consumers poll with agent-scope acquire loads. 32 blocks co-resident.

#define E_ 16
#define F_ 128
#define CH_ 128

typedef int i4 __attribute__((ext_vector_type(4)));
typedef _Float16 hf;
typedef hf hf2 __attribute__((ext_vector_type(2)));

__device__ __forceinline__ float sigf(float x) { return 1.0f / (1.0f + __expf(-x)); }
__device__ __forceinline__ float tanhf_(float x) {
  float e = __expf(2.0f * x);
  return 1.0f - 2.0f / (e + 1.0f);
}
__device__ __forceinline__ float lane_bcast(float v, int k) {
  return __int_as_float(__builtin_amdgcn_readlane(__float_as_int(v), k));
}
__device__ __forceinline__ int rl_i(int v, int k) {
  return __builtin_amdgcn_readlane(v, k);
}
__device__ __forceinline__ float fdot2(int a, int b, float c) {
#if __has_builtin(__builtin_amdgcn_fdot2)
  return __builtin_amdgcn_fdot2(__builtin_bit_cast(hf2, a),
                                __builtin_bit_cast(hf2, b), c, false);
#else
  float d;
  asm("v_dot2_f32_f16 %0, %1, %2, %3" : "=v"(d) : "v"(a), "v"(b), "v"(c));
  return d;
#endif
}
__device__ __forceinline__ int packh(float a, float b) {
  hf2 h; h.x = (hf)a; h.y = (hf)b;
  return __builtin_bit_cast(int, h);
}
// branchless act: cls==2 -> tanh(pre), else sigmoid(pre)
__device__ __forceinline__ float gate_act(float pre, int cls) {
  const float bb = (cls == 2) ? 2.0f : -1.0f;
  const float aa = (cls == 2) ? -2.0f : 1.0f;
  const float dd = (cls == 2) ? 1.0f : 0.0f;
  return dd + aa / (1.0f + __expf(bb * pre));
}
// LDS-only barrier (k2 role): ds visibility + sync; global loads stay in flight.
#define LDS_BARRIER()                                      \
  do {                                                     \
    asm volatile("s_waitcnt lgkmcnt(0)" ::: "memory");     \
    __builtin_amdgcn_s_barrier();                          \
    asm volatile("" ::: "memory");                         \
  } while (0)

// ---------------------------------------------------------------------------
__global__ void f2h_kernel(const float* __restrict__ src, hf* __restrict__ dst, int n) {
  int i = blockIdx.x * 256 + threadIdx.x;
  if (i < n) dst[i] = (hf)src[i];
}
// strided: dst[r*cols+c] = src[r*lds+c]
__global__ void f2h_str_kernel(const float* __restrict__ src, hf* __restrict__ dst,
                               int rows, int cols, int lds) {
  int i = blockIdx.x * 256 + threadIdx.x;
  if (i < rows * cols) {
    int r = i / cols, c = i - r * cols;
    dst[i] = (hf)src[(size_t)r * lds + c];
  }
}

// ---------------------------------------------------------------------------
// Generic skinny GEMM: C[m,n] = sum_k A[m,k]*W[n, co+k] (+b1[n]+b2[n])
// ---------------------------------------------------------------------------
__global__ __launch_bounds__(256) void gemm_k(
    const float* __restrict__ A, int lda,
    const float* __restrict__ W, int ldw, int co,
    const float* __restrict__ b1, const float* __restrict__ b2,
    float* __restrict__ C, int N, int K) {
  __shared__ float As[64 * 65];
  __shared__ float Ws[128 * 65];
  const int tid = threadIdx.x;
  const int m0 = blockIdx.x * 64;
  const int n0 = blockIdx.y * 128;
  const int rr = tid >> 4;
  const int c4 = (tid & 15) << 2;
  const int tm = tid >> 4;
  const int tn = tid & 15;

  float acc[4][8];
#pragma unroll
  for (int i = 0; i < 4; ++i)
#pragma unroll
    for (int j = 0; j < 8; ++j) acc[i][j] = 0.0f;

  for (int kk = 0; kk < K; kk += 64) {
#pragma unroll
    for (int p = 0; p < 4; ++p) {
      const int r = rr + p * 16;
      const float4 v = *(const float4*)(A + (size_t)(m0 + r) * lda + kk + c4);
      float* dst = &As[r * 65 + c4];
      dst[0] = v.x; dst[1] = v.y; dst[2] = v.z; dst[3] = v.w;
    }
#pragma unroll
    for (int p = 0; p < 8; ++p) {
      const int n = rr + p * 16;
      const float4 v = *(const float4*)(W + (size_t)(n0 + n) * ldw + co + kk + c4);
      float* dst = &Ws[n * 65 + c4];
      dst[0] = v.x; dst[1] = v.y; dst[2] = v.z; dst[3] = v.w;
    }
    __syncthreads();
#pragma unroll 4
    for (int k = 0; k < 64; ++k) {
      float a[4], wv[8];
#pragma unroll
      for (int i = 0; i < 4; ++i) a[i] = As[(tm * 4 + i) * 65 + k];
#pragma unroll
      for (int j = 0; j < 8; ++j) wv[j] = Ws[(tn * 8 + j) * 65 + k];
#pragma unroll
      for (int i = 0; i < 4; ++i)
#pragma unroll
        for (int j = 0; j < 8; ++j) acc[i][j] += a[i] * wv[j];
    }
    __syncthreads();
  }
#pragma unroll
  for (int i = 0; i < 4; ++i) {
    const int m = m0 + tm * 4 + i;
#pragma unroll
    for (int j = 0; j < 8; ++j) {
      const int n = n0 + tn * 8 + j;
      float v = acc[i][j];
      if (b1) v += b1[n];
      if (b2) v += b2[n];
      C[(size_t)m * N + n] = v;
    }
  }
}

// ---------------------------------------------------------------------------
// MEGA: blocks 0..15 k2-producer (R4 code + chunk flags); 16..31 comm+k4 consumer.
// ---------------------------------------------------------------------------
__global__ __launch_bounds__(576, 1) void mega(
    // k2 side
    const float* __restrict__ pg0, const float* __restrict__ preh,
    const float* __restrict__ prec,
    const hf* __restrict__ hWhh0, const hf* __restrict__ hWih1,
    const hf* __restrict__ hWhh1, const hf* __restrict__ hfcW,
    const float* __restrict__ bih1, const float* __restrict__ bhh1,
    const float* __restrict__ fcb, float* __restrict__ xout,
    // comm side
    const float* __restrict__ cWih0, const float* __restrict__ cbih0,
    const float* __restrict__ cbhh0,
    const hf* __restrict__ hCh0, const hf* __restrict__ hCi1,
    const hf* __restrict__ hCh1,
    const float* __restrict__ cbih1, const float* __restrict__ cbhh1,
    float* __restrict__ grp,
    // k4 side
    const float* __restrict__ pgo, const float* __restrict__ outh,
    const float* __restrict__ outc, const hf* __restrict__ hWo,
    const hf* __restrict__ hWg, float* __restrict__ noh,
    int* __restrict__ flagX, int* __restrict__ flagG, int B) {
  const int tid = threadIdx.x;
  const int wv = tid >> 6, l = tid & 63, cls = l >> 4, sub = l & 15;
  const int NCH = (B + CH_ - 1) / CH_;

  __shared__ __align__(8) hf h0s[2][64];
  __shared__ __align__(8) hf h1s[2][64];
  __shared__ float WtL[64 * 128];          // comm_Wih0^T: WtL[k*128 + row]
  __shared__ int grpP[CH_ * 32];           // packed fp16 grp chunk
  __shared__ __align__(8) hf hs[2][128];

  if (blockIdx.x < 16) {
    // =============== k2 role (verbatim R4 structure + chunk signaling) ======
    const int e = blockIdx.x;
    const bool isA = (wv < 4), isB = (wv >= 4 && wv < 8);
    const int wg = isA ? wv : (wv - 4);
    const int j = wg * 16 + sub;
    const int r = cls * 64 + j;

    int wa[32], wb[32];
    float bias = 0.f, c = 0.f;
    const float* pgp = nullptr;
    int jf = l;
    float fbias = 0.f;

    if (isA) {
      const i4* p0 = (const i4*)(hWhh0 + r * 64);
#pragma unroll
      for (int i = 0; i < 8; ++i) {
        i4 a = p0[i]; wa[4*i]=a.x; wa[4*i+1]=a.y; wa[4*i+2]=a.z; wa[4*i+3]=a.w;
      }
      pgp = pg0 + (size_t)e * 256 + r;
      if (cls == 1) { c = prec[e * 128 + j]; h0s[1][j] = (hf)preh[e * 128 + j]; }
    } else if (isB) {
      const i4* p1 = (const i4*)(hWih1 + r * 64);
      const i4* p2 = (const i4*)(hWhh1 + r * 64);
#pragma unroll
      for (int i = 0; i < 8; ++i) {
        i4 a = p1[i]; wa[4*i]=a.x; wa[4*i+1]=a.y; wa[4*i+2]=a.z; wa[4*i+3]=a.w;
        i4 b = p2[i]; wb[4*i]=b.x; wb[4*i+1]=b.y; wb[4*i+2]=b.z; wb[4*i+3]=b.w;
      }
      bias = bih1[r] + bhh1[r];
      if (cls == 1) { c = prec[e * 128 + 64 + j]; h1s[1][j] = (hf)preh[e * 128 + 64 + j]; }
    } else {
      const i4* pf = (const i4*)(hfcW + jf * 64);
#pragma unroll
      for (int i = 0; i < 8; ++i) {
        i4 a = pf[i]; wa[4*i]=a.x; wa[4*i+1]=a.y; wa[4*i+2]=a.z; wa[4*i+3]=a.w;
      }
      fbias = fcb[jf];
    }
    __syncthreads();

    auto doL0 = [&](int nn, float pgv) {
      const i4* hp = (const i4*)h0s[(nn + 1) & 1];
      float a0 = 0.f, a1 = 0.f, a2 = 0.f, a3 = 0.f;
#pragma unroll
      for (int i = 0; i < 8; ++i) {
        i4 h = hp[i];
        a0 = fdot2(wa[4*i],   h.x, a0); a1 = fdot2(wa[4*i+1], h.y, a1);
        a2 = fdot2(wa[4*i+2], h.z, a2); a3 = fdot2(wa[4*i+3], h.w, a3);
      }
      const float pre = (a0 + a1) + (a2 + a3) + pgv;
      const float act = gate_act(pre, cls);
      const float p32 = __shfl_xor(act, 32);
      const float ig = act * p32;
      const float p16 = __shfl_xor(ig, 16);
      if (cls == 1) {
        c = act * c + p16;
        h0s[nn & 1][j] = (hf)(p32 * tanhf_(c));
      }
    };
    auto doL1 = [&](int nn) {
      const i4* hp0 = (const i4*)h0s[(nn + 1) & 1];
      const i4* hp1 = (const i4*)h1s[nn & 1];
      float a0 = 0.f, a1 = 0.f, a2 = 0.f, a3 = 0.f;
#pragma unroll
      for (int i = 0; i < 8; ++i) {
        i4 h = hp0[i];
        a0 = fdot2(wa[4*i],   h.x, a0); a1 = fdot2(wa[4*i+1], h.y, a1);
        a2 = fdot2(wa[4*i+2], h.z, a2); a3 = fdot2(wa[4*i+3], h.w, a3);
      }
#pragma unroll
      for (int i = 0; i < 8; ++i) {
        i4 h = hp1[i];
        a0 = fdot2(wb[4*i],   h.x, a0); a1 = fdot2(wb[4*i+1], h.y, a1);
        a2 = fdot2(wb[4*i+2], h.z, a2); a3 = fdot2(wb[4*i+3], h.w, a3);
      }
      const float pre = (a0 + a1) + (a2 + a3) + bias;
      const float act = gate_act(pre, cls);
      const float p32 = __shfl_xor(act, 32);
      const float ig = act * p32;
      const float p16 = __shfl_xor(ig, 16);
      if (cls == 1) {
        c = act * c + p16;
        h1s[(nn + 1) & 1][j] = (hf)(p32 * tanhf_(c));
      }
    };
    auto doFC = [&](int nn) {   // wave 8 only (whole wave — no sinking hazard)
      const i4* hp1 = (const i4*)h1s[nn & 1];
      float a0 = 0.f, a1 = 0.f, a2 = 0.f, a3 = 0.f;
#pragma unroll
      for (int i = 0; i < 8; ++i) {
        i4 h = hp1[i];
        a0 = fdot2(wa[4*i],   h.x, a0); a1 = fdot2(wa[4*i+1], h.y, a1);
        a2 = fdot2(wa[4*i+2], h.z, a2); a3 = fdot2(wa[4*i+3], h.w, a3);
      }
      const float xv = (a0 + a1) + (a2 + a3) + fbias;
      xout[((size_t)(nn - 2) * E_ + e) * 64 + jf] = (xv > 0.f) ? xv : 0.05f * xv;
    };

    float pr0 = 0.f, pr1 = 0.f, pr2 = 0.f, pr3 = 0.f;
    if (isA) {
      pr0 = (0 < B) ? pgp[0] : 0.f;
      pr1 = (1 < B) ? pgp[(size_t)4096] : 0.f;
      pr2 = (2 < B) ? pgp[(size_t)2 * 4096] : 0.f;
      pr3 = (3 < B) ? pgp[(size_t)3 * 4096] : 0.f;
    }
    const int NT = (B + 2 + 3) & ~3;
    int sig = 0;

#define K2SUB(KK, PR)                                                \
    {                                                                \
      const int nn = n + KK;                                         \
      if (isA) {                                                     \
        if (nn < B) doL0(nn, PR);                                    \
        PR = (nn + 4 < B) ? pgp[(size_t)(nn + 4) * 4096] : 0.f;      \
      } else if (isB) {                                              \
        if (nn >= 1 && nn <= B) doL1(nn);                            \
      } else {                                                       \
        if (nn >= 2 && nn < B + 2) doFC(nn);                         \
      }                                                              \
      LDS_BARRIER();                                                 \
    }

    for (int n = 0; n < NT; n += 4) {
      while (sig < NCH && n >= (sig + 1) * CH_ + 2) {   // stores done for t<=n-3
        __syncthreads();                                 // drain all waves' stores
        if (tid == 0) { __threadfence(); atomicAdd(flagX + sig, 1); }
        ++sig;
      }
      K2SUB(0, pr0)
      K2SUB(1, pr1)
      K2SUB(2, pr2)
      K2SUB(3, pr3)
    }
#undef K2SUB
    while (sig < NCH) {
      __syncthreads();
      if (tid == 0) { __threadfence(); atomicAdd(flagX + sig, 1); }
      ++sig;
    }
  } else {
    // =============== consumer role: comm (phase A/B) + out-LSTM (phase C) ===
    const int e4 = blockIdx.x - 16;
    const int j4 = (wv < 8) ? (wv * 16 + sub) : 0;   // elem 0..127
    const int r4 = cls * 128 + j4;                   // out-gate row

    // stage comm_Wih0^T into LDS (fp32): WtL[k*128+row] = Wih0[row][k]
    for (int u = tid; u < 8192; u += 576) {
      const int row = u >> 6, k = u & 63;
      WtL[k * 128 + row] = cWih0[u];
    }
    // chain weights (fp16 packed): rows l and l+64, 16 dwords each matrix
    int wh0a[16], wh0b[16], wi1a[16], wi1b[16], wh1a[16], wh1b[16];
    {
      const i4* a0 = (const i4*)(hCh0 + l * 32);
      const i4* b0 = (const i4*)(hCh0 + (l + 64) * 32);
      const i4* a1 = (const i4*)(hCi1 + l * 32);
      const i4* b1 = (const i4*)(hCi1 + (l + 64) * 32);
      const i4* a2 = (const i4*)(hCh1 + l * 32);
      const i4* b2 = (const i4*)(hCh1 + (l + 64) * 32);
#pragma unroll
      for (int i = 0; i < 4; ++i) {
        i4 v;
        v = a0[i]; wh0a[4*i]=v.x; wh0a[4*i+1]=v.y; wh0a[4*i+2]=v.z; wh0a[4*i+3]=v.w;
        v = b0[i]; wh0b[4*i]=v.x; wh0b[4*i+1]=v.y; wh0b[4*i+2]=v.z; wh0b[4*i+3]=v.w;
        v = a1[i]; wi1a[4*i]=v.x; wi1a[4*i+1]=v.y; wi1a[4*i+2]=v.z; wi1a[4*i+3]=v.w;
        v = b1[i]; wi1b[4*i]=v.x; wi1b[4*i+1]=v.y; wi1b[4*i+2]=v.z; wi1b[4*i+3]=v.w;
        v = a2[i]; wh1a[4*i]=v.x; wh1a[4*i+1]=v.y; wh1a[4*i+2]=v.z; wh1a[4*i+3]=v.w;
        v = b2[i]; wh1b[4*i]=v.x; wh1b[4*i+1]=v.y; wh1b[4*i+2]=v.z; wh1b[4*i+3]=v.w;
      }
    }
    const float ba0 = cbih0[l] + cbhh0[l];
    const float bb0 = cbih0[l + 64] + cbhh0[l + 64];
    const float cb1a = cbih1[l] + cbhh1[l];
    const float cb1b = cbih1[l + 64] + cbhh1[l + 64];

    float c4v = 0.f;
    if (wv < 8 && cls == 1) {
      c4v = outc[e4 * 128 + j4];
      hs[1][j4] = (hf)outh[e4 * 128 + j4];
    }
    __syncthreads();

    for (int ci = 0; ci < NCH; ++ci) {
      // ---- wait for producer chunk
      if (tid == 0) {
        while (__hip_atomic_load(flagX + ci, __ATOMIC_ACQUIRE,
                                 __HIP_MEMORY_SCOPE_AGENT) < 16)
          __builtin_amdgcn_s_sleep(8);
      }
      __syncthreads();
      // ---- phase A: comm chain, one wave per timestep
      const int t = ci * CH_ + e4 * 8 + wv;
      if (wv < 8 && t < B) {
        float h0 = 0.f, c0 = 0.f, h1 = 0.f, c1 = 0.f, al = 1.f;
        const float* xb = xout + (size_t)t * (E_ * 64);
        for (int r3 = 0; r3 < 3; ++r3) {
          for (int e2 = 0; e2 < E_; ++e2) {
            // gih = x@Wih0^T + b (fp32, LDS weights, x broadcast)
            const float xl = xb[e2 * 64 + l];
            float ga = ba0, gb = bb0;
#pragma unroll
            for (int k = 0; k < 64; ++k) {
              const float xv = lane_bcast(xl, k);
              ga += WtL[k * 128 + l] * xv;
              gb += WtL[k * 128 + 64 + l] * xv;
            }
            // + Whh0 @ h0 (fp16 dot2, packed broadcast)
            {
              const int hp0 = packh(h0, __shfl_xor(h0, 1));
#pragma unroll
              for (int m = 0; m < 16; ++m) {
                const int s = rl_i(hp0, 2 * m);
                ga = fdot2(wh0a[m], s, ga);
                gb = fdot2(wh0b[m], s, gb);
              }
            }
            {
              const float fa = __shfl_xor(ga, 32);
              const float ob = __shfl_xor(gb, 32);
              c0 = sigf(fa) * c0 + al * sigf(ga) * tanhf_(gb);
              h0 = sigf(ob) * tanhf_(c0);
            }
            // layer1: Wih1@h0 + Whh1@h1 + b
            float g1a = cb1a, g1b = cb1b;
            {
              const int hp0n = packh(h0, __shfl_xor(h0, 1));
              const int hp1 = packh(h1, __shfl_xor(h1, 1));
#pragma unroll
              for (int m = 0; m < 16; ++m) {
                const int s0 = rl_i(hp0n, 2 * m);
                const int s1 = rl_i(hp1, 2 * m);
                g1a = fdot2(wi1a[m], s0, g1a); g1b = fdot2(wi1b[m], s0, g1b);
                g1a = fdot2(wh1a[m], s1, g1a); g1b = fdot2(wh1b[m], s1, g1b);
              }
            }
            {
              const float fa = __shfl_xor(g1a, 32);
              const float ob = __shfl_xor(g1b, 32);
              c1 = sigf(fa) * c1 + al * sigf(g1a) * tanhf_(g1b);
              h1 = sigf(ob) * tanhf_(c1);
            }
          }
          al *= 0.333f;
        }
        if (l < 32) {
          grp[(size_t)t * 64 + l] = c0;
          grp[(size_t)t * 64 + 32 + l] = c1;
        }
      }
      __syncthreads();   // drain grp stores (all waves)
      if (tid == 0) {
        __threadfence();
        atomicAdd(flagG + ci, 1);
        while (__hip_atomic_load(flagG + ci, __ATOMIC_ACQUIRE,
                                 __HIP_MEMORY_SCOPE_AGENT) < 16)
          __builtin_amdgcn_s_sleep(8);
      }
      __syncthreads();
      // ---- phase B: stage grp chunk -> LDS packed fp16
      {
        const int base = ci * CH_;
        for (int u = tid; u < CH_ * 32; u += 576) {
          const int ti = u >> 5, m = u & 31;
          const int tg = base + ti;
          float f0 = 0.f, f1 = 0.f;
          if (tg < B) {
            f0 = grp[(size_t)tg * 64 + 2 * m];
            f1 = grp[(size_t)tg * 64 + 2 * m + 1];
          }
          grpP[ti * 32 + m] = packh(f0, f1);
        }
      }
      // phase-C weights (per chunk; L1-resident reloads)
      int w4[64], wg4[32];
      if (wv < 8) {
        const i4* pw = (const i4*)(hWo + (size_t)r4 * 128);
#pragma unroll
        for (int i = 0; i < 16; ++i) {
          i4 a = pw[i]; w4[4*i]=a.x; w4[4*i+1]=a.y; w4[4*i+2]=a.z; w4[4*i+3]=a.w;
        }
        const i4* pg_ = (const i4*)(hWg + (size_t)r4 * 64);
#pragma unroll
        for (int i = 0; i < 8; ++i) {
          i4 a = pg_[i]; wg4[4*i]=a.x; wg4[4*i+1]=a.y; wg4[4*i+2]=a.z; wg4[4*i+3]=a.w;
        }
      }
      __syncthreads();
      // ---- phase C: out-LSTM recurrence over the chunk
      const int base = ci * CH_;
      const int steps = (B - base < CH_) ? (B - base) : CH_;
      const float* pgoP = pgo + (size_t)e4 * 512 + r4;
      float po0 = 0.f, po1 = 0.f;
      if (wv < 8) {
        po0 = pgoP[(size_t)base * 8192];
        if (steps > 1) po1 = pgoP[(size_t)(base + 1) * 8192];
      }
      for (int s = 0; s < steps; ++s) {
        const int ng = base + s;
        if (wv < 8) {
          float a0 = 0.f, a1 = 0.f, a2 = 0.f, a3 = 0.f;
          // gg in-flight: grp[t] . outWih_group_row[r4]
          const i4* gp = (const i4*)&grpP[s * 32];
#pragma unroll
          for (int m = 0; m < 8; ++m) {
            i4 g = gp[m];
            a0 = fdot2(wg4[4*m],   g.x, a0); a1 = fdot2(wg4[4*m+1], g.y, a1);
            a2 = fdot2(wg4[4*m+2], g.z, a2); a3 = fdot2(wg4[4*m+3], g.w, a3);
          }
          const i4* hp = (const i4*)hs[(ng + 1) & 1];
#pragma unroll
          for (int k = 0; k < 16; ++k) {
            i4 h = hp[k];
            a0 = fdot2(w4[4*k],   h.x, a0); a1 = fdot2(w4[4*k+1], h.y, a1);
            a2 = fdot2(w4[4*k+2], h.z, a2); a3 = fdot2(w4[4*k+3], h.w, a3);
          }
          const float poC = (s + 2 < steps) ? pgoP[(size_t)(ng + 2) * 8192] : 0.f;
          const float pre = (a0 + a1) + (a2 + a3) + po0;   // pgo has biases
          const float act = gate_act(pre, cls);
          const float p32 = __shfl_xor(act, 32);
          const float ig = act * p32;
          const float p16 = __shfl_xor(ig, 16);
          if (cls == 1) {
            c4v = act * c4v + p16;
            const float h = p32 * tanhf_(c4v);
            hs[ng & 1][j4] = (hf)h;
            noh[((size_t)ng * E_ + e4) * 128 + j4] = h;
          }
          po0 = po1; po1 = poC;
        }
        __syncthreads();
      }
    }
  }
}

// ---------------------------------------------------------------------------
// K5: heads. tar = softmax(noh@tarW^T + tb) [64], dir = softmax(noh@dirW^T + db) [3].
// ---------------------------------------------------------------------------
__global__ __launch_bounds__(256) void k5_heads(
    const float* __restrict__ noh, const float* __restrict__ tarW,
    const float* __restrict__ tarb, const float* __restrict__ dirW,
    const float* __restrict__ dirb, float* __restrict__ out) {
  __shared__ float tw[128 * 64];
  __shared__ float tb[64];
  const int tid = threadIdx.x;
  for (int idx = tid; idx < 8192; idx += 256) {
    const int j = idx >> 7, k = idx & 127;
    tw[k * 64 + j] = tarW[idx];
  }
  if (tid < 64) tb[tid] = tarb[tid];
  __syncthreads();
  const int w = tid >> 6, l = tid & 63;
  const float db0 = dirb[0], db1 = dirb[1], db2 = dirb[2];

  for (int p = 0; p < 16; ++p) {
    const int row = blockIdx.x * 64 + p * 4 + w;
    const float na = noh[(size_t)row * 128 + l];
    const float nb = noh[(size_t)row * 128 + 64 + l];
    float acc = tb[l];
#pragma unroll
    for (int k = 0; k < 64; ++k) acc += tw[k * 64 + l] * lane_bcast(na, k);
#pragma unroll
    for (int k = 0; k < 64; ++k) acc += tw[(64 + k) * 64 + l] * lane_bcast(nb, k);
    float m = acc;
#pragma unroll
    for (int s = 32; s; s >>= 1) m = fmaxf(m, __shfl_xor(m, s));
    const float ex = __expf(acc - m);
    float sm = ex;
#pragma unroll
    for (int s = 32; s; s >>= 1) sm += __shfl_xor(sm, s);
    out[(size_t)row * 67 + l] = ex / sm;
    float d0 = dirW[l] * na + dirW[64 + l] * nb;
    float d1 = dirW[128 + l] * na + dirW[192 + l] * nb;
    float d2 = dirW[256 + l] * na + dirW[320 + l] * nb;
#pragma unroll
    for (int s = 32; s; s >>= 1) {
      d0 += __shfl_xor(d0, s);
      d1 += __shfl_xor(d1, s);
      d2 += __shfl_xor(d2, s);
    }
    d0 += db0; d1 += db1; d2 += db2;
    const float dm = fmaxf(d0, fmaxf(d1, d2));
    const float e0 = __expf(d0 - dm), e1 = __expf(d1 - dm), e2 = __expf(d2 - dm);
    const float ds = e0 + e1 + e2;
    if (l < 3) out[(size_t)row * 67 + 64 + l] = (l == 0 ? e0 : (l == 1 ? e1 : e2)) / ds;
  }
}

// ---------------------------------------------------------------------------
extern "C" void kernel_launch(void* const* d_in, const int* in_sizes, int n_in,
                              void* d_out, int out_size, void* d_ws, size_t ws_size,
                              hipStream_t stream) {
  const float* features = (const float*)d_in[0];
  const float* pre_h    = (const float*)d_in[1];
  const float* pre_c    = (const float*)d_in[2];
  const float* out_h    = (const float*)d_in[3];
  const float* out_c    = (const float*)d_in[4];
  const float* pre_Wih0 = (const float*)d_in[5];
  const float* pre_Whh0 = (const float*)d_in[6];
  const float* pre_bih0 = (const float*)d_in[7];
  const float* pre_bhh0 = (const float*)d_in[8];
  const float* pre_Wih1 = (const float*)d_in[9];
  const float* pre_Whh1 = (const float*)d_in[10];
  const float* pre_bih1 = (const float*)d_in[11];
  const float* pre_bhh1 = (const float*)d_in[12];
  const float* fc_W     = (const float*)d_in[13];
  const float* fc_b     = (const float*)d_in[14];
  const float* comm_Wih0 = (const float*)d_in[15];
  const float* comm_Whh0 = (const float*)d_in[16];
  const float* comm_bih0 = (const float*)d_in[17];
  const float* comm_bhh0 = (const float*)d_in[18];
  const float* comm_Wih1 = (const float*)d_in[19];
  const float* comm_Whh1 = (const float*)d_in[20];
  const float* comm_bih1 = (const float*)d_in[21];
  const float* comm_bhh1 = (const float*)d_in[22];
  const float* out_Wih  = (const float*)d_in[23];
  const float* out_Whh  = (const float*)d_in[24];
  const float* out_bih  = (const float*)d_in[25];
  const float* out_bhh  = (const float*)d_in[26];
  const float* tar_W    = (const float*)d_in[27];
  const float* tar_b    = (const float*)d_in[28];
  const float* dir_W    = (const float*)d_in[29];
  const float* dir_b    = (const float*)d_in[30];

  const int B = in_sizes[0] / (E_ * F_);   // 2048
  float* ws = (float*)d_ws;
  float* pg0 = ws;                                  // [B*16, 256]
  float* pgo = pg0 + (size_t)B * E_ * 256;          // [B*16, 512]
  float* xbf = pgo + (size_t)B * E_ * 512;          // [B*16, 64]
  float* grp = xbf + (size_t)B * E_ * 64;           // [B, 64]
  float* noh = grp + (size_t)B * 64;                // [B*16, 128]
  hf* hWhh0 = (hf*)(noh + (size_t)B * E_ * 128);    // [256*64]
  hf* hWih1 = hWhh0 + 256 * 64;
  hf* hWhh1 = hWih1 + 256 * 64;
  hf* hfcW  = hWhh1 + 256 * 64;                     // [64*64]
  hf* hWo   = hfcW + 64 * 64;                       // [512*128]
  hf* hWg   = hWo + 512 * 128;                      // [512*64]
  hf* hCh0  = hWg + 512 * 64;                       // [128*32]
  hf* hCi1  = hCh0 + 128 * 32;
  hf* hCh1  = hCi1 + 128 * 32;
  int* flags = (int*)(hCh1 + 128 * 32);             // flagX[64] + flagG[64]
  int* flagX = flags;
  int* flagG = flags + 64;
  (void)ws_size; (void)n_in; (void)out_size;

  hipMemsetAsync(flags, 0, 128 * sizeof(int), stream);

  // fp16 weight packs
  f2h_kernel<<<(256 * 64 + 255) / 256, 256, 0, stream>>>(pre_Whh0, hWhh0, 256 * 64);
  f2h_kernel<<<(256 * 64 + 255) / 256, 256, 0, stream>>>(pre_Wih1, hWih1, 256 * 64);
  f2h_kernel<<<(256 * 64 + 255) / 256, 256, 0, stream>>>(pre_Whh1, hWhh1, 256 * 64);
  f2h_kernel<<<(64 * 64 + 255) / 256, 256, 0, stream>>>(fc_W, hfcW, 64 * 64);
  f2h_kernel<<<(512 * 128 + 255) / 256, 256, 0, stream>>>(out_Whh, hWo, 512 * 128);
  f2h_str_kernel<<<(512 * 64 + 255) / 256, 256, 0, stream>>>(out_Wih, hWg, 512, 64, 192);
  f2h_kernel<<<(128 * 32 + 255) / 256, 256, 0, stream>>>(comm_Whh0, hCh0, 128 * 32);
  f2h_kernel<<<(128 * 32 + 255) / 256, 256, 0, stream>>>(comm_Wih1, hCi1, 128 * 32);
  f2h_kernel<<<(128 * 32 + 255) / 256, 256, 0, stream>>>(comm_Whh1, hCh1, 128 * 32);

  const int MB = B * E_ / 64;
  // G1: pre-LSTM layer0 input projection (+ both biases)
  gemm_k<<<dim3(MB, 2), 256, 0, stream>>>(features, 128, pre_Wih0, 128, 0,
                                          pre_bih0, pre_bhh0, pg0, 256, 128);
  // G2: out-LSTM feat-half input projection (+ both biases)
  gemm_k<<<dim3(MB, 4), 256, 0, stream>>>(features, 128, out_Wih, 192, 64,
                                          out_bih, out_bhh, pgo, 512, 128);
  // MEGA: k2 producer ∥ comm+k4 consumer
  mega<<<32, 576, 0, stream>>>(
      pg0, pre_h, pre_c, hWhh0, hWih1, hWhh1, hfcW, pre_bih1, pre_bhh1, fc_b,
      xbf,
      comm_Wih0, comm_bih0, comm_bhh0, hCh0, hCi1, hCh1, comm_bih1, comm_bhh1,
      grp,
      pgo, out_h, out_c, hWo, hWg, noh, flagX, flagG, B);
  // K5: heads
  k5_heads<<<B * E_ / 64, 256, 0, stream>>>(noh, tar_W, tar_b, dir_W, dir_b,
                                            (float*)d_out);
}

// Round 9
// 2999.764 us; speedup vs baseline: 5.8750x; 5.8750x over previous
//
#include <hip/hip_runtime.h>
#include <hip/hip_bf16.h>

// alphaLSTMNetwork: B=2048 sequential steps, E=16 elevators.
//   G1: pg0  = feat @ pre_Wih0^T + bih0 + bhh0            [B*16, 256]  (parallel)
//   G2: pgo  = feat @ out_Wih[:,64:]^T + bih + bhh        [B*16, 512]  (parallel)
//   K2: per-elevator 2-layer pre-LSTM + fc recurrence     (16 blocks, seq over t)
//   G4: gih  = x @ comm_Wih0^T + bih0 + bhh0              [B*16, 128]  (parallel)
//   K3: comm alpha-LSTM, 48 micro-steps, state resets/t   (1 wave per t, parallel)
//   G6: gg   = group @ out_Wih[:,:64]^T                   [B, 512]     (parallel)
//   K4: per-elevator out-LSTM recurrence                  (16 blocks, seq over t)
//   K5: heads (tar/dir softmax)                           (parallel)
// R9 = R3 (best-known-good, 3199us) + ONE change: the 4 gates of an element
// now live in one DPP quad (cls = l&3, elem = wave*16 + (l>>2)); the two
// per-step ds_swizzle __shfl_xor(32)/(16) gathers become quad_perm DPP
// butterflies 0x4E (xor2) / 0xB1 (xor1) — full-rate VALU, no LDS pipe,
// unambiguous semantics. Arithmetic per element is bit-identical to R3.
// (R8 post-mortem: mega-kernel fusion spilled ~200 weight VGPRs to scratch —
// WRITE_SIZE 100MB vs 25MB real — never fuse roles with disjoint reg sets.)

#define E_ 16
#define F_ 128

typedef int i4 __attribute__((ext_vector_type(4)));
typedef _Float16 hf;
typedef hf hf2 __attribute__((ext_vector_type(2)));

__device__ __forceinline__ float sigf(float x) { return 1.0f / (1.0f + __expf(-x)); }
__device__ __forceinline__ float tanhf_(float x) {
  float e = __expf(2.0f * x);
  return 1.0f - 2.0f / (e + 1.0f);
}
__device__ __forceinline__ float lane_bcast(float v, int k) {
  return __int_as_float(__builtin_amdgcn_readlane(__float_as_int(v), k));
}
__device__ __forceinline__ float fdot2(int a, int b, float c) {
#if __has_builtin(__builtin_amdgcn_fdot2)
  return __builtin_amdgcn_fdot2(__builtin_bit_cast(hf2, a),
                                __builtin_bit_cast(hf2, b), c, false);
#else
  float d;
  asm("v_dot2_f32_f16 %0, %1, %2, %3" : "=v"(d) : "v"(a), "v"(b), "v"(c));
  return d;
#endif
}

// Canonical DPP quad_perm butterflies (full-rate VALU, no LDS pipe).
// 0xB1 = quad_perm(1,0,3,2) -> lane^1 ; 0x4E = quad_perm(2,3,0,1) -> lane^2.
__device__ __forceinline__ float dpp_xor1(float x) {
  return __int_as_float(__builtin_amdgcn_update_dpp(
      __float_as_int(x), __float_as_int(x), 0xB1, 0xF, 0xF, true));
}
__device__ __forceinline__ float dpp_xor2(float x) {
  return __int_as_float(__builtin_amdgcn_update_dpp(
      __float_as_int(x), __float_as_int(x), 0x4E, 0xF, 0xF, true));
}

// ---------------------------------------------------------------------------
// fp32 -> fp16 weight conversion (one-time per call, tiny)
// ---------------------------------------------------------------------------
__global__ void f2h_kernel(const float* __restrict__ src, hf* __restrict__ dst, int n) {
  int i = blockIdx.x * 256 + threadIdx.x;
  if (i < n) dst[i] = (hf)src[i];
}

// ---------------------------------------------------------------------------
// Generic skinny GEMM: C[m,n] = sum_k A[m,k]*W[n, co+k] (+b1[n]+b2[n])
// ---------------------------------------------------------------------------
__global__ __launch_bounds__(256) void gemm_k(
    const float* __restrict__ A, int lda,
    const float* __restrict__ W, int ldw, int co,
    const float* __restrict__ b1, const float* __restrict__ b2,
    float* __restrict__ C, int N, int K) {
  __shared__ float As[64 * 65];
  __shared__ float Ws[128 * 65];
  const int tid = threadIdx.x;
  const int m0 = blockIdx.x * 64;
  const int n0 = blockIdx.y * 128;
  const int rr = tid >> 4;
  const int c4 = (tid & 15) << 2;
  const int tm = tid >> 4;
  const int tn = tid & 15;

  float acc[4][8];
#pragma unroll
  for (int i = 0; i < 4; ++i)
#pragma unroll
    for (int j = 0; j < 8; ++j) acc[i][j] = 0.0f;

  for (int kk = 0; kk < K; kk += 64) {
#pragma unroll
    for (int p = 0; p < 4; ++p) {
      const int r = rr + p * 16;
      const float4 v = *(const float4*)(A + (size_t)(m0 + r) * lda + kk + c4);
      float* dst = &As[r * 65 + c4];
      dst[0] = v.x; dst[1] = v.y; dst[2] = v.z; dst[3] = v.w;
    }
#pragma unroll
    for (int p = 0; p < 8; ++p) {
      const int n = rr + p * 16;
      const float4 v = *(const float4*)(W + (size_t)(n0 + n) * ldw + co + kk + c4);
      float* dst = &Ws[n * 65 + c4];
      dst[0] = v.x; dst[1] = v.y; dst[2] = v.z; dst[3] = v.w;
    }
    __syncthreads();
#pragma unroll 4
    for (int k = 0; k < 64; ++k) {
      float a[4], wv[8];
#pragma unroll
      for (int i = 0; i < 4; ++i) a[i] = As[(tm * 4 + i) * 65 + k];
#pragma unroll
      for (int j = 0; j < 8; ++j) wv[j] = Ws[(tn * 8 + j) * 65 + k];
#pragma unroll
      for (int i = 0; i < 4; ++i)
#pragma unroll
        for (int j = 0; j < 8; ++j) acc[i][j] += a[i] * wv[j];
    }
    __syncthreads();
  }
#pragma unroll
  for (int i = 0; i < 4; ++i) {
    const int m = m0 + tm * 4 + i;
#pragma unroll
    for (int j = 0; j < 8; ++j) {
      const int n = n0 + tn * 8 + j;
      float v = acc[i][j];
      if (b1) v += b1[n];
      if (b2) v += b2[n];
      C[(size_t)m * N + n] = v;
    }
  }
}

// ---------------------------------------------------------------------------
// K2: per-elevator pre-LSTM (2 layers) + fc. 16 blocks x 576 threads (9 waves).
// Waves 0-3 (A): L0 step n.  Waves 4-7 (B): L1 step n-1.  Wave 8 (C): fc step n-2.
// QUAD layout: lane cls = l&3 owns gate cls (i,f,g,o) of elem j = wg*16+(l>>2);
// gate gather via DPP quad_perm xor2 then xor1; f-lane (cls1) owns c.
// ONE __syncthreads per step; h0s/h1s double-buffered fp16 in LDS.
// ---------------------------------------------------------------------------
__global__ __launch_bounds__(576) void k2_pre(
    const float* __restrict__ pg0, const float* __restrict__ preh,
    const float* __restrict__ prec,
    const hf* __restrict__ hWhh0, const hf* __restrict__ hWih1,
    const hf* __restrict__ hWhh1, const hf* __restrict__ hfcW,
    const float* __restrict__ bih1, const float* __restrict__ bhh1,
    const float* __restrict__ fcb, float* __restrict__ xout, int B) {
  const int e = blockIdx.x, tid = threadIdx.x;
  const int wv = tid >> 6, l = tid & 63;
  const int cls = l & 3;              // gate class within the quad: i,f,g,o
  __shared__ __align__(16) hf h0s[2][64];
  __shared__ __align__(16) hf h1s[2][64];

  int wa[32], wb[32];
  float bias = 0.f, c = 0.f;
  const float* pgp = nullptr;
  int j = 0;

  if (wv < 4) {                       // group A: L0
    j = wv * 16 + (l >> 2);
    const int r = cls * 64 + j;
    const i4* p0 = (const i4*)(hWhh0 + r * 64);
#pragma unroll
    for (int i = 0; i < 8; ++i) {
      i4 a = p0[i]; wa[4*i]=a.x; wa[4*i+1]=a.y; wa[4*i+2]=a.z; wa[4*i+3]=a.w;
    }
    pgp = pg0 + (size_t)e * 256 + r;
    if (cls == 1) { c = prec[e * 128 + j]; h0s[1][j] = (hf)preh[e * 128 + j]; }
  } else if (wv < 8) {                // group B: L1
    j = (wv - 4) * 16 + (l >> 2);
    const int r = cls * 64 + j;
    const i4* p1 = (const i4*)(hWih1 + r * 64);
    const i4* p2 = (const i4*)(hWhh1 + r * 64);
#pragma unroll
    for (int i = 0; i < 8; ++i) {
      i4 a = p1[i]; wa[4*i]=a.x; wa[4*i+1]=a.y; wa[4*i+2]=a.z; wa[4*i+3]=a.w;
      i4 b = p2[i]; wb[4*i]=b.x; wb[4*i+1]=b.y; wb[4*i+2]=b.z; wb[4*i+3]=b.w;
    }
    bias = bih1[cls * 64 + j] + bhh1[cls * 64 + j];
    if (cls == 1) { c = prec[e * 128 + 64 + j]; h1s[1][j] = (hf)preh[e * 128 + 64 + j]; }
  } else {                            // group C: fc
    j = l;
    const i4* pf = (const i4*)(hfcW + l * 64);
#pragma unroll
    for (int i = 0; i < 8; ++i) {
      i4 a = pf[i]; wa[4*i]=a.x; wa[4*i+1]=a.y; wa[4*i+2]=a.z; wa[4*i+3]=a.w;
    }
    bias = fcb[l];
  }
  __syncthreads();

  auto doL0 = [&](int nn, float pgv) {
    const i4* hp = (const i4*)h0s[(nn + 1) & 1];          // h0(nn-1)
    float a0 = 0.f, a1 = 0.f, a2 = 0.f, a3 = 0.f;
#pragma unroll
    for (int i = 0; i < 8; ++i) {
      i4 h = hp[i];
      a0 = fdot2(wa[4*i],   h.x, a0); a1 = fdot2(wa[4*i+1], h.y, a1);
      a2 = fdot2(wa[4*i+2], h.z, a2); a3 = fdot2(wa[4*i+3], h.w, a3);
    }
    const float pre = (a0 + a1) + (a2 + a3) + pgv;        // pg0 has x-part+biases
    const float act = (cls == 2) ? tanhf_(pre) : sigf(pre);
    const float p2 = dpp_xor2(act);                       // cls0<-tanh(g), cls1<-sig(o)
    const float ig = act * p2;                            // cls0: sig(i)*tanh(g)
    const float p1 = dpp_xor1(ig);                        // cls1<-ig
    if (cls == 1) {
      c = act * c + p1;                                   // act = sig(f)
      h0s[nn & 1][j] = (hf)(p2 * tanhf_(c));              // p2 = sig(o)
    }
  };
  auto doL1 = [&](int nn) {
    const i4* hp0 = (const i4*)h0s[(nn + 1) & 1];         // h0(nn-1)
    const i4* hp1 = (const i4*)h1s[nn & 1];               // h1(nn-2)
    float a0 = 0.f, a1 = 0.f, a2 = 0.f, a3 = 0.f;
#pragma unroll
    for (int i = 0; i < 8; ++i) {
      i4 h = hp0[i];
      a0 = fdot2(wa[4*i],   h.x, a0); a1 = fdot2(wa[4*i+1], h.y, a1);
      a2 = fdot2(wa[4*i+2], h.z, a2); a3 = fdot2(wa[4*i+3], h.w, a3);
    }
#pragma unroll
    for (int i = 0; i < 8; ++i) {
      i4 h = hp1[i];
      a0 = fdot2(wb[4*i],   h.x, a0); a1 = fdot2(wb[4*i+1], h.y, a1);
      a2 = fdot2(wb[4*i+2], h.z, a2); a3 = fdot2(wb[4*i+3], h.w, a3);
    }
    const float pre = (a0 + a1) + (a2 + a3) + bias;
    const float act = (cls == 2) ? tanhf_(pre) : sigf(pre);
    const float p2 = dpp_xor2(act);
    const float ig = act * p2;
    const float p1 = dpp_xor1(ig);
    if (cls == 1) {
      c = act * c + p1;
      h1s[(nn + 1) & 1][j] = (hf)(p2 * tanhf_(c));        // h1(nn-1) -> buf (nn-1)&1
    }
  };
  auto doFC = [&](int nn) {
    const i4* hp1 = (const i4*)h1s[nn & 1];               // h1(nn-2)
    float a0 = 0.f, a1 = 0.f, a2 = 0.f, a3 = 0.f;
#pragma unroll
    for (int i = 0; i < 8; ++i) {
      i4 h = hp1[i];
      a0 = fdot2(wa[4*i],   h.x, a0); a1 = fdot2(wa[4*i+1], h.y, a1);
      a2 = fdot2(wa[4*i+2], h.z, a2); a3 = fdot2(wa[4*i+3], h.w, a3);
    }
    const float xv = (a0 + a1) + (a2 + a3) + bias;
    xout[((size_t)(nn - 2) * E_ + e) * 64 + l] = (xv > 0.f) ? xv : 0.05f * xv;
  };

  float pgA = 0.f, pgB = 0.f;
  if (wv < 4) { pgA = pgp[0]; if (B > 1) pgB = pgp[4096]; }

  for (int n = 0; n < B + 2; ++n) {
    if (wv < 4) {
      if (n < B) {
        const float pgC = (n + 2 < B) ? pgp[(size_t)(n + 2) * 4096] : 0.f;
        doL0(n, pgA);
        pgA = pgB; pgB = pgC;
      }
    } else if (wv < 8) {
      if (n >= 1 && n <= B) doL1(n);
    } else {
      if (n >= 2) doFC(n);
    }
    __syncthreads();
  }
}

// ---------------------------------------------------------------------------
// K3: communication alpha-LSTM. One wave per timestep t (state resets each t).
// ---------------------------------------------------------------------------
__global__ __launch_bounds__(256) void k3_comm(
    const float* __restrict__ gih0, const float* __restrict__ Whh0,
    const float* __restrict__ Wih1, const float* __restrict__ Whh1,
    const float* __restrict__ bih1, const float* __restrict__ bhh1,
    float* __restrict__ grp, int B) {
  const int w = threadIdx.x >> 6;
  const int l = threadIdx.x & 63;
  const int t = blockIdx.x * 4 + w;

  float wh0a[32], wh0b[32], wi1a[32], wi1b[32], wh1a[32], wh1b[32];
#pragma unroll
  for (int i = 0; i < 32; ++i) {
    wh0a[i] = Whh0[l * 32 + i];         wh0b[i] = Whh0[(l + 64) * 32 + i];
    wi1a[i] = Wih1[l * 32 + i];         wi1b[i] = Wih1[(l + 64) * 32 + i];
    wh1a[i] = Whh1[l * 32 + i];         wh1b[i] = Whh1[(l + 64) * 32 + i];
  }
  const float cb1a = bih1[l] + bhh1[l];
  const float cb1b = bih1[l + 64] + bhh1[l + 64];

  float h0 = 0.0f, c0 = 0.0f, h1 = 0.0f, c1 = 0.0f;
  float al = 1.0f;
  const float* gbase = gih0 + (size_t)t * (E_ * 128);
  for (int r = 0; r < 3; ++r) {
    for (int e = 0; e < E_; ++e) {
      float ga = gbase[e * 128 + l];
      float gb = gbase[e * 128 + l + 64];
#pragma unroll
      for (int k = 0; k < 32; ++k) {
        const float hv = lane_bcast(h0, k);
        ga += wh0a[k] * hv;
        gb += wh0b[k] * hv;
      }
      {
        const float fa = __shfl_xor(ga, 32);
        const float ob = __shfl_xor(gb, 32);
        c0 = sigf(fa) * c0 + al * sigf(ga) * tanhf_(gb);
        h0 = sigf(ob) * tanhf_(c0);
      }
      float ga1 = cb1a, gb1 = cb1b;
#pragma unroll
      for (int k = 0; k < 32; ++k) {
        const float hv = lane_bcast(h0, k);
        ga1 += wi1a[k] * hv;
        gb1 += wi1b[k] * hv;
      }
#pragma unroll
      for (int k = 0; k < 32; ++k) {
        const float hv = lane_bcast(h1, k);
        ga1 += wh1a[k] * hv;
        gb1 += wh1b[k] * hv;
      }
      {
        const float fa = __shfl_xor(ga1, 32);
        const float ob = __shfl_xor(gb1, 32);
        c1 = sigf(fa) * c1 + al * sigf(ga1) * tanhf_(gb1);
        h1 = sigf(ob) * tanhf_(c1);
      }
    }
    al *= 0.333f;
  }
  if (l < 32) {
    grp[(size_t)t * 64 + l] = c0;
    grp[(size_t)t * 64 + 32 + l] = c1;
  }
}

// ---------------------------------------------------------------------------
// K4: per-elevator out-LSTM. 16 blocks x 512 threads (8 waves).
// QUAD layout: elem j = wave*16+(l>>2), gate cls=l&3, row r=cls*128+j;
// 64 dot2/thread. Gate gather via DPP xor2/xor1; f-lane owns c;
// ONE barrier/step. Raw depth-2 prefetch of pgo/gg rows.
// ---------------------------------------------------------------------------
__global__ __launch_bounds__(512) void k4_out(
    const float* __restrict__ pgo, const float* __restrict__ gg,
    const float* __restrict__ outh, const float* __restrict__ outc,
    const hf* __restrict__ hWo, float* __restrict__ noh, int B) {
  const int e = blockIdx.x, tid = threadIdx.x;
  const int wv = tid >> 6, l = tid & 63;
  const int cls = l & 3;
  const int j = wv * 16 + (l >> 2);
  const int r = cls * 128 + j;
  __shared__ __align__(16) hf hs[2][128];

  int w[64];
  {
    const i4* pw = (const i4*)(hWo + (size_t)r * 128);
#pragma unroll
    for (int i = 0; i < 16; ++i) {
      i4 a = pw[i]; w[4*i]=a.x; w[4*i+1]=a.y; w[4*i+2]=a.z; w[4*i+3]=a.w;
    }
  }
  float c = 0.f;
  if (cls == 1) { c = outc[e * 128 + j]; hs[1][j] = (hf)outh[e * 128 + j]; }
  __syncthreads();

  const float* pgoP = pgo + (size_t)e * 512 + r;   // + tt*8192
  const float* ggP  = gg + r;                      // + tt*512
  float poA = pgoP[0], gA = ggP[0];
  float poB = 0.f, gB = 0.f;
  if (B > 1) { poB = pgoP[8192]; gB = ggP[512]; }

  for (int n = 0; n < B; ++n) {
    float poC = 0.f, gC = 0.f;
    if (n + 2 < B) { poC = pgoP[(size_t)(n + 2) * 8192]; gC = ggP[(size_t)(n + 2) * 512]; }
    const i4* hp = (const i4*)hs[(n + 1) & 1];       // h(n-1)
    float a0 = 0.f, a1 = 0.f, a2 = 0.f, a3 = 0.f;
#pragma unroll
    for (int i = 0; i < 16; ++i) {
      i4 h = hp[i];
      a0 = fdot2(w[4*i],   h.x, a0); a1 = fdot2(w[4*i+1], h.y, a1);
      a2 = fdot2(w[4*i+2], h.z, a2); a3 = fdot2(w[4*i+3], h.w, a3);
    }
    const float pre = (a0 + a1) + (a2 + a3) + poA + gA;  // pgo has biases
    const float act = (cls == 2) ? tanhf_(pre) : sigf(pre);
    const float p2 = dpp_xor2(act);                      // cls0<-tanh(g), cls1<-sig(o)
    const float ig = act * p2;
    const float p1 = dpp_xor1(ig);                       // cls1<-ig
    if (cls == 1) {
      c = act * c + p1;
      const float h = p2 * tanhf_(c);
      hs[n & 1][j] = (hf)h;
      noh[((size_t)n * E_ + e) * 128 + j] = h;
    }
    __syncthreads();
    poA = poB; gA = gB; poB = poC; gB = gC;
  }
}

// ---------------------------------------------------------------------------
// K5: heads. tar = softmax(noh@tarW^T + tb) [64], dir = softmax(noh@dirW^T + db) [3].
// ---------------------------------------------------------------------------
__global__ __launch_bounds__(256) void k5_heads(
    const float* __restrict__ noh, const float* __restrict__ tarW,
    const float* __restrict__ tarb, const float* __restrict__ dirW,
    const float* __restrict__ dirb, float* __restrict__ out) {
  __shared__ float tw[128 * 64];
  __shared__ float tb[64];
  const int tid = threadIdx.x;
  for (int idx = tid; idx < 8192; idx += 256) {
    const int j = idx >> 7, k = idx & 127;
    tw[k * 64 + j] = tarW[idx];
  }
  if (tid < 64) tb[tid] = tarb[tid];
  __syncthreads();
  const int w = tid >> 6, l = tid & 63;
  const float db0 = dirb[0], db1 = dirb[1], db2 = dirb[2];

  for (int p = 0; p < 16; ++p) {
    const int row = blockIdx.x * 64 + p * 4 + w;
    const float na = noh[(size_t)row * 128 + l];
    const float nb = noh[(size_t)row * 128 + 64 + l];
    float acc = tb[l];
#pragma unroll
    for (int k = 0; k < 64; ++k) acc += tw[k * 64 + l] * lane_bcast(na, k);
#pragma unroll
    for (int k = 0; k < 64; ++k) acc += tw[(64 + k) * 64 + l] * lane_bcast(nb, k);
    float m = acc;
#pragma unroll
    for (int s = 32; s; s >>= 1) m = fmaxf(m, __shfl_xor(m, s));
    const float ex = __expf(acc - m);
    float sm = ex;
#pragma unroll
    for (int s = 32; s; s >>= 1) sm += __shfl_xor(sm, s);
    out[(size_t)row * 67 + l] = ex / sm;
    float d0 = dirW[l] * na + dirW[64 + l] * nb;
    float d1 = dirW[128 + l] * na + dirW[192 + l] * nb;
    float d2 = dirW[256 + l] * na + dirW[320 + l] * nb;
#pragma unroll
    for (int s = 32; s; s >>= 1) {
      d0 += __shfl_xor(d0, s);
      d1 += __shfl_xor(d1, s);
      d2 += __shfl_xor(d2, s);
    }
    d0 += db0; d1 += db1; d2 += db2;
    const float dm = fmaxf(d0, fmaxf(d1, d2));
    const float e0 = __expf(d0 - dm), e1 = __expf(d1 - dm), e2 = __expf(d2 - dm);
    const float ds = e0 + e1 + e2;
    if (l < 3) out[(size_t)row * 67 + 64 + l] = (l == 0 ? e0 : (l == 1 ? e1 : e2)) / ds;
  }
}

// ---------------------------------------------------------------------------
extern "C" void kernel_launch(void* const* d_in, const int* in_sizes, int n_in,
                              void* d_out, int out_size, void* d_ws, size_t ws_size,
                              hipStream_t stream) {
  const float* features = (const float*)d_in[0];
  const float* pre_h    = (const float*)d_in[1];
  const float* pre_c    = (const float*)d_in[2];
  const float* out_h    = (const float*)d_in[3];
  const float* out_c    = (const float*)d_in[4];
  const float* pre_Wih0 = (const float*)d_in[5];
  const float* pre_Whh0 = (const float*)d_in[6];
  const float* pre_bih0 = (const float*)d_in[7];
  const float* pre_bhh0 = (const float*)d_in[8];
  const float* pre_Wih1 = (const float*)d_in[9];
  const float* pre_Whh1 = (const float*)d_in[10];
  const float* pre_bih1 = (const float*)d_in[11];
  const float* pre_bhh1 = (const float*)d_in[12];
  const float* fc_W     = (const float*)d_in[13];
  const float* fc_b     = (const float*)d_in[14];
  const float* comm_Wih0 = (const float*)d_in[15];
  const float* comm_Whh0 = (const float*)d_in[16];
  const float* comm_bih0 = (const float*)d_in[17];
  const float* comm_bhh0 = (const float*)d_in[18];
  const float* comm_Wih1 = (const float*)d_in[19];
  const float* comm_Whh1 = (const float*)d_in[20];
  const float* comm_bih1 = (const float*)d_in[21];
  const float* comm_bhh1 = (const float*)d_in[22];
  const float* out_Wih  = (const float*)d_in[23];
  const float* out_Whh  = (const float*)d_in[24];
  const float* out_bih  = (const float*)d_in[25];
  const float* out_bhh  = (const float*)d_in[26];
  const float* tar_W    = (const float*)d_in[27];
  const float* tar_b    = (const float*)d_in[28];
  const float* dir_W    = (const float*)d_in[29];
  const float* dir_b    = (const float*)d_in[30];

  const int B = in_sizes[0] / (E_ * F_);   // 2048
  float* ws = (float*)d_ws;
  float* pg0 = ws;                                  // [B*16, 256]
  float* pgo = pg0 + (size_t)B * E_ * 256;          // [B*16, 512]
  float* xbf = pgo + (size_t)B * E_ * 512;          // [B*16, 64]
  float* gih = xbf + (size_t)B * E_ * 64;           // [B*16, 128]
  float* grp = gih + (size_t)B * E_ * 128;          // [B, 64]
  float* gg  = grp + (size_t)B * 64;                // [B, 512]
  float* noh = gg + (size_t)B * 512;                // [B*16, 128]
  hf* hWhh0 = (hf*)(noh + (size_t)B * E_ * 128);    // [256*64]
  hf* hWih1 = hWhh0 + 256 * 64;                     // [256*64]
  hf* hWhh1 = hWih1 + 256 * 64;                     // [256*64]
  hf* hfcW  = hWhh1 + 256 * 64;                     // [64*64]
  hf* hWo   = hfcW + 64 * 64;                       // [512*128]
  (void)ws_size; (void)n_in; (void)out_size;

  // W0: fp32 -> fp16 weight packs for the recurrence kernels
  f2h_kernel<<<(256 * 64 + 255) / 256, 256, 0, stream>>>(pre_Whh0, hWhh0, 256 * 64);
  f2h_kernel<<<(256 * 64 + 255) / 256, 256, 0, stream>>>(pre_Wih1, hWih1, 256 * 64);
  f2h_kernel<<<(256 * 64 + 255) / 256, 256, 0, stream>>>(pre_Whh1, hWhh1, 256 * 64);
  f2h_kernel<<<(64 * 64 + 255) / 256, 256, 0, stream>>>(fc_W, hfcW, 64 * 64);
  f2h_kernel<<<(512 * 128 + 255) / 256, 256, 0, stream>>>(out_Whh, hWo, 512 * 128);

  const int MB = B * E_ / 64;

  // G1: pre-LSTM layer0 input projection (+ both biases)
  gemm_k<<<dim3(MB, 2), 256, 0, stream>>>(features, 128, pre_Wih0, 128, 0,
                                          pre_bih0, pre_bhh0, pg0, 256, 128);
  // G2: out-LSTM feat-half input projection (+ both biases)
  gemm_k<<<dim3(MB, 4), 256, 0, stream>>>(features, 128, out_Wih, 192, 64,
                                          out_bih, out_bhh, pgo, 512, 128);
  // K2: pre recurrence (writes x)
  k2_pre<<<E_, 576, 0, stream>>>(pg0, pre_h, pre_c, hWhh0, hWih1, hWhh1, hfcW,
                                 pre_bih1, pre_bhh1, fc_b, xbf, B);
  // G4: comm layer0 input projection (+ both biases)
  gemm_k<<<dim3(MB, 1), 256, 0, stream>>>(xbf, 64, comm_Wih0, 64, 0,
                                          comm_bih0, comm_bhh0, gih, 128, 64);
  // K3: comm chains (writes group cell states)
  k3_comm<<<B / 4, 256, 0, stream>>>(gih, comm_Whh0, comm_Wih1, comm_Whh1,
                                     comm_bih1, comm_bhh1, grp, B);
  // G6: out-LSTM group-half input projection
  gemm_k<<<dim3(B / 64, 4), 256, 0, stream>>>(grp, 64, out_Wih, 192, 0,
                                              nullptr, nullptr, gg, 512, 64);
  // K4: out recurrence (writes noh)
  k4_out<<<E_, 512, 0, stream>>>(pgo, gg, out_h, out_c, hWo, noh, B);
  // K5: heads + softmax -> d_out [B,16,67]
  k5_heads<<<B * E_ / 64, 256, 0, stream>>>(noh, tar_W, tar_b, dir_W, dir_b,
                                            (float*)d_out);
}